// Round 15
// baseline (7945.831 us; speedup 1.0000x reference)
//
#include <hip/hip_runtime.h>
#include <hip/hip_fp16.h>
#include <stdint.h>

// LSTM, E=2048, B=2, T=2048, ALL I/O float32 (per reference dtypes).
// For t>=1 input==h, so gates = h @ (W_ih+W_hh)^T + (b_ih+b_hh).
// v16 = v15 (best, 7714us: lstm 7300 + proj 414) + two micro-opts:
//  - lstm tail: pls re-layout [64 rowsel=row*2+b][12] -> wave0's serial
//    tail reads 2xb128 (8 floats, 7 adds) instead of 4xb128 (16 floats).
//    Writers: 8 b32 stores pre-barrier (parallel waves, off critical path).
//  - proj: software-pipelined Wout stream (prefetch next kc's weights)
//    to overlap the global stream with LDS+dot2.
// Step budget (measured v15): 3.56us = 0.43 FMA-issue + ~0.5 reduce/tail
// + ~2.5 exchange (store->LLC->poll RTT x global-max over 256 producers).
// Weight capacity (131KB/block in VGPRs at the 512-thr/128-VGPR cap)
// forces the 256-block full-chip topology -> exchange is structural.
// Kept (verified 6x): f16 packed weights in VGPRs (v_fma_mix), fp32 h in
// padded LDS (stride 36), 16B chunks [pay_b0|tag|pay_b1|tag] (4 dwordx4
// polls/lane), parallel-gate tail, vmcnt(0)+sleep cadence with
// reloads-before-sleep, lgkmcnt-only deposit sync, ONE __syncthreads/step,
// single coalesced 128B publish (v9 law), c in registers, sc0 sc1
// LLC-direct exchange, publish-before-seqout. Protocol: tag-validated
// (poison 0xAAAAAAAA never matches tags 1..2047), relaxed, no fences.
// chk: [parity(2)][2048 chunks] x 16B = 64KB.

#define E 2048
#define NBLK 256
#define NTHR 512
#define HLDS_B 2304            // padded floats per batch: 64 slices * 36
#define PLS_PAR 768            // floats per parity: 64 rowsel * 12
#define SMEM_MAIN 24704        // 18432 hlds + 6144 pls + 128 bias
#define SMEM_PROJ 131072

typedef uint32_t u32;
typedef unsigned long long u64;
typedef unsigned int u32x4 __attribute__((ext_vector_type(4)));
typedef _Float16 hf2 __attribute__((ext_vector_type(2)));

__device__ __forceinline__ float sigf(float x){
  return __builtin_amdgcn_rcpf(1.0f + __expf(-x));
}
__device__ __forceinline__ float tanhfast(float x){
  // 1 - 2/(e^{2x}+1); exp overflow -> rcp(inf)=0 -> 1; underflow -> -1.
  float e = __expf(2.0f * x);
  return 1.0f - 2.0f * __builtin_amdgcn_rcpf(e + 1.0f);
}
__device__ __forceinline__ u32 f16p(float lo, float hi){
  return (u32)__half_as_ushort(__float2half_rn(lo))
       | ((u32)__half_as_ushort(__float2half_rn(hi)) << 16);
}
__device__ __forceinline__ float dot2(u32 a, u32 b, float acc){
  return __builtin_amdgcn_fdot2(__builtin_bit_cast(hf2, a),
                                __builtin_bit_cast(hf2, b), acc, false);
}

// one row x 8 k, both batches: 16 FMAs from 4 packed-f16 weight pairs
#define ROWFMA8(W0, W1, W2, W3, A0, A1) \
  A0 = fmaf(__low2float(W0),  p0.x, A0); A0 = fmaf(__high2float(W0), p0.y, A0); \
  A0 = fmaf(__low2float(W1),  p0.z, A0); A0 = fmaf(__high2float(W1), p0.w, A0); \
  A0 = fmaf(__low2float(W2),  p1.x, A0); A0 = fmaf(__high2float(W2), p1.y, A0); \
  A0 = fmaf(__low2float(W3),  p1.z, A0); A0 = fmaf(__high2float(W3), p1.w, A0); \
  A1 = fmaf(__low2float(W0),  q0.x, A1); A1 = fmaf(__high2float(W0), q0.y, A1); \
  A1 = fmaf(__low2float(W1),  q0.z, A1); A1 = fmaf(__high2float(W1), q0.w, A1); \
  A1 = fmaf(__low2float(W2),  q1.x, A1); A1 = fmaf(__high2float(W2), q1.y, A1); \
  A1 = fmaf(__low2float(W3),  q1.z, A1); A1 = fmaf(__high2float(W3), q1.w, A1);

// tag-check both 8B halves of chunk slot J (QJ = [pay0,tag0,pay1,tag1])
#define CHKQ(J, QJ) \
  if (pend & (1 << (2*(J)))){ \
    if ((QJ).y == tag){ \
      hlds[cd0[J]] = __uint_as_float((QJ).x); pend &= ~(1 << (2*(J))); } } \
  if (pend & (2 << (2*(J)))){ \
    if ((QJ).w == tag){ \
      hlds[cd1[J]] = __uint_as_float((QJ).z); pend &= ~(2 << (2*(J))); } }

// 4 LLC-direct dwordx4 samples (1 KB contiguous per wave per load)
#define ISSUE4Q(Q0, Q1, Q2, Q3) \
  asm volatile( \
    "global_load_dwordx4 %0, %4, off sc0 sc1\n\t" \
    "global_load_dwordx4 %1, %4, off offset:1024 sc0 sc1\n\t" \
    "global_load_dwordx4 %2, %4, off offset:2048 sc0 sc1\n\t" \
    "global_load_dwordx4 %3, %4, off offset:3072 sc0 sc1" \
    : "=&v"(Q0), "=&v"(Q1), "=&v"(Q2), "=&v"(Q3) \
    : "v"(src) : "memory")

// exec-masked reload of chunk J if either half pending
#define RELOADQ(J, QJ, OFS) \
  if (pend & (3 << (2*(J)))){ \
    asm volatile("global_load_dwordx4 %0, %1, off offset:" OFS " sc0 sc1" \
                 : "=v"(QJ) : "v"(src) : "memory"); \
  }

__global__ void __launch_bounds__(NTHR, 1) lstm_kernel(
    const float* __restrict__ xin, const float* __restrict__ Wih,
    const float* __restrict__ Whh, const float* __restrict__ bih,
    const float* __restrict__ bhh, u32x4* __restrict__ chk16,
    float* __restrict__ seqout)
{
  extern __shared__ char smem[];
  float* hlds = (float*)smem;                    // [2][2304] = 18432 B (padded h)
  float* pls  = (float*)(smem + 18432);          // [2][768]  =  6144 B partials
  float* bias = (float*)(smem + 24576);          // [32]

  const int tid  = threadIdx.x;
  const int blk  = blockIdx.x;
  const int e0   = blk << 3;                     // this block owns h elems e0..e0+7
  const int lane = tid & 63;
  const int wv   = tid >> 6;                     // wave 0..7, k-slice [wv*256, +256)
  const int rg   = lane >> 3;                    // row group: rows rg*4..rg*4+3
  const int ksl  = lane & 7;                     // 32-k sub-slice within wave
  const int ks   = (wv << 3) + ksl;              // global 32-k slice 0..63
  const int k0   = ks << 5;

  if (tid < 32){
    const int grow = ((tid >> 3) << 11) + e0 + (tid & 7);
    bias[tid] = bih[grow] + bhh[grow];
  }
  // x for t=0, written in the padded h layout
  for (int i = tid; i < 2 * E; i += NTHR){
    const int b = i >> 11, k = i & 2047;
    hlds[b * HLDS_B + (k >> 5) * 36 + (k & 31)] = xin[i];
  }
  __syncthreads();

  const float* hb0 = hlds + ks * 36;             // batch 0, own 32-k slice
  const float* hb1 = hlds + HLDS_B + ks * 36;    // batch 1

  // ---- fused: build f16 Wc = Wih + Whh into registers (64 half2) AND
  //      compute t=0 gates = x @ W_ih^T in full fp32 (h=0 at t=0) ----
  __half2 wh[64];
  float acc0[4] = {0.f, 0.f, 0.f, 0.f};
  float acc1[4] = {0.f, 0.f, 0.f, 0.f};
  #pragma unroll
  for (int rr = 0; rr < 4; ++rr){
    const int row  = (rg << 2) + rr;             // 0..31 = gate*8 + eoff
    const int grow = ((row >> 3) << 11) + e0 + (row & 7);
    const float* pa = Wih + (size_t)grow * E + k0;
    const float* pb = Whh + (size_t)grow * E + k0;
    #pragma unroll
    for (int c = 0; c < 8; ++c){                 // 4 k per chunk
      float4 a = *(const float4*)(pa + (c << 2));
      float4 b = *(const float4*)(pb + (c << 2));
      wh[(rr << 4) + (c << 1)    ] =
        __halves2half2(__float2half_rn(a.x + b.x), __float2half_rn(a.y + b.y));
      wh[(rr << 4) + (c << 1) + 1] =
        __halves2half2(__float2half_rn(a.z + b.z), __float2half_rn(a.w + b.w));
      float4 x0 = *(const float4*)(hb0 + (c << 2));
      float4 x1 = *(const float4*)(hb1 + (c << 2));
      acc0[rr] = fmaf(a.x, x0.x, acc0[rr]); acc0[rr] = fmaf(a.y, x0.y, acc0[rr]);
      acc0[rr] = fmaf(a.z, x0.z, acc0[rr]); acc0[rr] = fmaf(a.w, x0.w, acc0[rr]);
      acc1[rr] = fmaf(a.x, x1.x, acc1[rr]); acc1[rr] = fmaf(a.y, x1.y, acc1[rr]);
      acc1[rr] = fmaf(a.z, x1.z, acc1[rr]); acc1[rr] = fmaf(a.w, x1.w, acc1[rr]);
    }
  }

  const float br = bias[lane & 31];              // hoisted (used by wave 0)
  float creg = 0.0f;                             // cell state (cell lanes)

  // poll mapping: chunk c == element e; wave wv polls its own k-slice
  // [wv*256, +256): 4 chunks/lane, each load = 1 KB contiguous per wave.
  int cd0[4], cd1[4];
  #pragma unroll
  for (int j = 0; j < 4; ++j){
    const int e = (wv << 8) + (j << 6) + lane;
    cd0[j] = (e >> 5) * 36 + (e & 31);           // batch 0 deposit
    cd1[j] = HLDS_B + cd0[j];                    // batch 1 deposit
  }

  // tail addressing: rowsel = row*2 + b, slot stride 12 floats (48B-aligned)
  const int rdsel = ((lane & 31) << 1) | (lane >> 5);

  for (int t = 0; t < 2048; ++t){
    // wave-level pre-reduce across the 8 k-sub-slices (ksl = lane bits 0..2)
    #pragma unroll
    for (int m = 1; m <= 4; m <<= 1){
      #pragma unroll
      for (int rr = 0; rr < 4; ++rr){
        acc0[rr] += __shfl_xor(acc0[rr], m, 64);
        acc1[rr] += __shfl_xor(acc1[rr], m, 64);
      }
    }
    if (ksl == 0){                               // 8 lanes/wave publish partials
      float* pw = pls + (t & 1) * PLS_PAR;
      #pragma unroll
      for (int rr = 0; rr < 4; ++rr){
        const int row2 = ((rg << 2) + rr) << 1;
        pw[row2 * 12 + wv]        = acc0[rr];    // b=0 slot
        pw[(row2 + 1) * 12 + wv]  = acc1[rr];    // b=1 slot
      }
    }
    __syncthreads();                             // the ONLY barrier per step

    if (wv == 0){                                // parallel-gate tail
      const int r = lane & 31;                   // row = gate*8 + eoff
      const int b = lane >> 5;
      const float* rp = pls + (t & 1) * PLS_PAR + rdsel * 12;
      float4 v0 = *(const float4*)(rp);          // 2 x b128: 8 wave-partials
      float4 v1 = *(const float4*)(rp + 4);
      float s = br + v0.x + v0.y + v0.z + v0.w + v1.x + v1.y + v1.z + v1.w;
      // own gate's nonlinearity in parallel: tanh(s) = 2*sig(2s)-1 (g==2)
      const int g = r >> 3;                      // 0=i, 1=f, 2=g, 3=o
      const float arg = (g == 2) ? (s + s) : s;
      const float t0v = sigf(arg);
      const float nl  = (g == 2) ? (2.0f * t0v - 1.0f) : t0v;
      const float SF = __shfl(nl, (lane + 8)  & 63, 64);   // sig(f) to cell lanes
      const float TG = __shfl(nl, (lane + 16) & 63, 64);   // tanh(g)
      const float SO = __shfl(nl, (lane + 24) & 63, 64);   // sig(o)
      if (r < 8){                                // cell lanes (g==0: nl=sig(i))
        const float cn = SF * creg + nl * TG;
        const float hn = SO * tanhfast(cn);
        creg = cn;
        const u32 h32 = __float_as_uint(hn);
        const u32 oth = (u32)__shfl((int)h32, (lane + 32) & 63, 64);  // b1 value
        if (t < 2047 && b == 0){                 // publish: ONE 128B store
          const u32 tg = (u32)(t + 1);
          u32x4 pk; pk.x = h32; pk.y = tg; pk.z = oth; pk.w = tg;
          u32x4* dst = chk16 + (((t + 1) & 1) << 11) + e0 + lane;
          asm volatile("global_store_dwordx4 %0, %1, off sc0 sc1"
                       :: "v"(dst), "v"(pk) : "memory");
        }
        seqout[(((size_t)b << 11) + (size_t)t) * E + e0 + r] = hn;
      }
    }
    if (t == 2047) break;

    {   // poll: LLC-direct 4x dwordx4; reloads issued BEFORE sleep
      const u32x4* src = (const u32x4*)chk16 + (((t + 1) & 1) << 11)
                       + (wv << 8) + lane;
      const u32 tag = (u32)(t + 1);
      u32x4 q0, q1, q2, q3;
      ISSUE4Q(q0, q1, q2, q3);
      asm volatile("s_waitcnt vmcnt(0)" ::: "memory");
      int pend = 0xFF;
      while (true){
        CHKQ(0, q0) CHKQ(1, q1) CHKQ(2, q2) CHKQ(3, q3)
        if (pend == 0) break;
        RELOADQ(0, q0, "0")    RELOADQ(1, q1, "1024")
        RELOADQ(2, q2, "2048") RELOADQ(3, q3, "3072")
        __builtin_amdgcn_s_sleep(1);
        asm volatile("s_waitcnt vmcnt(0)" ::: "memory");
      }
      // own ds_writes visible to all lanes of this wave (wave-synchronous)
      asm volatile("s_waitcnt lgkmcnt(0)" ::: "memory");
      __builtin_amdgcn_sched_barrier(0);
    }

    // compute acc(t+1): h @ Wc^T, weights in f16 registers
    #pragma unroll
    for (int rr = 0; rr < 4; ++rr){ acc0[rr] = 0.f; acc1[rr] = 0.f; }
    #pragma unroll
    for (int c8 = 0; c8 < 4; ++c8){              // 8 k per chunk
      float4 p0 = *(const float4*)(hb0 + (c8 << 3));
      float4 p1 = *(const float4*)(hb0 + (c8 << 3) + 4);
      float4 q0 = *(const float4*)(hb1 + (c8 << 3));
      float4 q1 = *(const float4*)(hb1 + (c8 << 3) + 4);
      #pragma unroll
      for (int rr = 0; rr < 4; ++rr){
        ROWFMA8(wh[(rr << 4) + (c8 << 2)],     wh[(rr << 4) + (c8 << 2) + 1],
                wh[(rr << 4) + (c8 << 2) + 2], wh[(rr << 4) + (c8 << 2) + 3],
                acc0[rr], acc1[rr]);
      }
    }
  }
}

// Wout f32 -> packed f16 (one-shot pre-pass into workspace).
// Grid: E*E / (256*8) = 2048 blocks EXACTLY (v14's 4096 was OOB).
__global__ void wout_cvt(const float* __restrict__ w, u32* __restrict__ o)
{
  const size_t i = (((size_t)blockIdx.x << 8) + threadIdx.x) << 3;  // 8 floats
  float4 a = *(const float4*)(w + i);
  float4 b = *(const float4*)(w + i + 4);
  uint4 r;
  r.x = f16p(a.x, a.y); r.y = f16p(a.z, a.w);
  r.z = f16p(b.x, b.y); r.w = f16p(b.z, b.w);
  *(uint4*)(o + (i >> 1)) = r;
}

// proj PAIR path, f16 Wout + v_dot2 + software-pipelined weight stream:
// blocks 2b,2b+1 share rows 32b..+31 (f16-staged from WS seq, 128 KB LDS);
// block computes one 1024-col half, 2 cols/thread, 512 thr (2 waves/SIMD).
__global__ void __launch_bounds__(512, 1) proj_pair16(
    const float* __restrict__ src, float* __restrict__ io,
    const u32* __restrict__ wf, const float* __restrict__ bout)
{
  extern __shared__ char smem[];
  u32* ah = (u32*)smem;                        // [32 rows][1024] half2 = 128 KB
  const int tid = threadIdx.x;
  const int blk = blockIdx.x;
  const size_t rbase = (size_t)(blk >> 1) * 32 * E;
  const int ch = (blk & 1) << 10;              // column-half base

  for (int idx = tid; idx < 32768; idx += 512){   // 32*2048 halves / 2
    const float2 v = *(const float2*)(src + rbase + ((size_t)idx << 1));
    ah[idx] = f16p(v.x, v.y);
  }
  __syncthreads();

  const int n0 = ch + tid;                     // 2 cols: n0, n0+512
  const int n1 = n0 + 512;
  const u32* wr0 = wf + (size_t)n0 * 1024;     // 1024 u32 (2048 halves) per row
  const u32* wr1 = wf + (size_t)n1 * 1024;
  float acc0[32], acc1[32];
  #pragma unroll
  for (int m = 0; m < 32; ++m){ acc0[m] = 0.0f; acc1[m] = 0.0f; }

  uint4 wa = *(const uint4*)(wr0);             // prefetched weight pair
  uint4 wb = *(const uint4*)(wr1);
  for (int kc = 0; kc < 256; ++kc){            // 8 k per iter
    uint4 wa_n, wb_n;
    if (kc < 255){                             // prefetch next while computing
      wa_n = *(const uint4*)(wr0 + ((kc + 1) << 2));
      wb_n = *(const uint4*)(wr1 + ((kc + 1) << 2));
    }
    const u32* hp = ah + (kc << 2);
    #pragma unroll
    for (int m = 0; m < 32; ++m){
      const uint4 hv = *(const uint4*)(hp + (m << 10));  // 8 halves, broadcast
      acc0[m] = dot2(wa.x, hv.x, acc0[m]);
      acc0[m] = dot2(wa.y, hv.y, acc0[m]);
      acc0[m] = dot2(wa.z, hv.z, acc0[m]);
      acc0[m] = dot2(wa.w, hv.w, acc0[m]);
      acc1[m] = dot2(wb.x, hv.x, acc1[m]);
      acc1[m] = dot2(wb.y, hv.y, acc1[m]);
      acc1[m] = dot2(wb.z, hv.z, acc1[m]);
      acc1[m] = dot2(wb.w, hv.w, acc1[m]);
    }
    wa = wa_n; wb = wb_n;
  }
  const float bo0 = bout[n0];
  const float bo1 = bout[n1];
  #pragma unroll
  for (int m = 0; m < 32; ++m){
    io[rbase + ((size_t)m << 11) + n0] = acc0[m] + bo0;
    io[rbase + ((size_t)m << 11) + n1] = acc1[m] + bo1;
  }
}

// Fallback 1 (v13-proven): pair path, f32 Wout.
__global__ void __launch_bounds__(512, 1) proj_pair_kernel(
    const float* __restrict__ src, float* __restrict__ io,
    const float* __restrict__ Wout, const float* __restrict__ bout)
{
  extern __shared__ char smem[];
  u32* ah = (u32*)smem;
  const int tid = threadIdx.x;
  const int blk = blockIdx.x;
  const size_t rbase = (size_t)(blk >> 1) * 32 * E;
  const int ch = (blk & 1) << 10;

  for (int idx = tid; idx < 32768; idx += 512){
    const float2 v = *(const float2*)(src + rbase + ((size_t)idx << 1));
    ah[idx] = f16p(v.x, v.y);
  }
  __syncthreads();

  const int n0 = ch + tid;
  const int n1 = n0 + 512;
  const float* wr0 = Wout + (size_t)n0 * E;
  const float* wr1 = Wout + (size_t)n1 * E;
  float acc0[32], acc1[32];
  #pragma unroll
  for (int m = 0; m < 32; ++m){ acc0[m] = 0.0f; acc1[m] = 0.0f; }
  for (int kc = 0; kc < 256; ++kc){
    const float4 a0v = *(const float4*)(wr0 + (kc << 3));
    const float4 a1v = *(const float4*)(wr0 + (kc << 3) + 4);
    const float4 b0v = *(const float4*)(wr1 + (kc << 3));
    const float4 b1v = *(const float4*)(wr1 + (kc << 3) + 4);
    const u32* hp = ah + (kc << 2);
    #pragma unroll
    for (int m = 0; m < 32; ++m){
      const uint4 hv = *(const uint4*)(hp + (m << 10));
      const __half2 h0 = __builtin_bit_cast(__half2, hv.x);
      const __half2 h1 = __builtin_bit_cast(__half2, hv.y);
      const __half2 h2 = __builtin_bit_cast(__half2, hv.z);
      const __half2 h3 = __builtin_bit_cast(__half2, hv.w);
      const float x0 = __low2float(h0), x1 = __high2float(h0);
      const float x2 = __low2float(h1), x3 = __high2float(h1);
      const float x4 = __low2float(h2), x5 = __high2float(h2);
      const float x6 = __low2float(h3), x7 = __high2float(h3);
      acc0[m] = fmaf(a0v.x, x0, acc0[m]); acc0[m] = fmaf(a0v.y, x1, acc0[m]);
      acc0[m] = fmaf(a0v.z, x2, acc0[m]); acc0[m] = fmaf(a0v.w, x3, acc0[m]);
      acc0[m] = fmaf(a1v.x, x4, acc0[m]); acc0[m] = fmaf(a1v.y, x5, acc0[m]);
      acc0[m] = fmaf(a1v.z, x6, acc0[m]); acc0[m] = fmaf(a1v.w, x7, acc0[m]);
      acc1[m] = fmaf(b0v.x, x0, acc1[m]); acc1[m] = fmaf(b0v.y, x1, acc1[m]);
      acc1[m] = fmaf(b0v.z, x2, acc1[m]); acc1[m] = fmaf(b0v.w, x3, acc1[m]);
      acc1[m] = fmaf(b1v.x, x4, acc1[m]); acc1[m] = fmaf(b1v.y, x5, acc1[m]);
      acc1[m] = fmaf(b1v.z, x6, acc1[m]); acc1[m] = fmaf(b1v.w, x7, acc1[m]);
    }
  }
  const float bo0 = bout[n0];
  const float bo1 = bout[n1];
  #pragma unroll
  for (int m = 0; m < 32; ++m){
    io[rbase + ((size_t)m << 11) + n0] = acc0[m] + bo0;
    io[rbase + ((size_t)m << 11) + n1] = acc1[m] + bo1;
  }
}

// Fallback 2 (v10-proven, tiny ws): in-place, 16 rows f32-staged.
__global__ void __launch_bounds__(256, 1) proj_kernel(
    float* __restrict__ io, const float* __restrict__ Wout,
    const float* __restrict__ bout)
{
  extern __shared__ char smem[];
  float* alds = (float*)smem;
  const int tid = threadIdx.x;
  const size_t rbase = (size_t)blockIdx.x * 16 * E;

  for (int idx = tid; idx < 8192; idx += 256){
    float4 v = *(const float4*)(io + rbase + ((size_t)idx << 2));
    *(float4*)(alds + (idx << 2)) = v;
  }
  __syncthreads();

  for (int p = 0; p < 2; ++p){
    const int n0 = (p << 10) + tid;
    const int n1 = n0 + 256;
    const int n2 = n0 + 512;
    const int n3 = n0 + 768;
    const float* wr0 = Wout + (size_t)n0 * E;
    const float* wr1 = Wout + (size_t)n1 * E;
    const float* wr2 = Wout + (size_t)n2 * E;
    const float* wr3 = Wout + (size_t)n3 * E;
    float acc0[16], acc1[16], acc2[16], acc3[16];
    #pragma unroll
    for (int m = 0; m < 16; ++m){
      acc0[m] = 0.0f; acc1[m] = 0.0f; acc2[m] = 0.0f; acc3[m] = 0.0f;
    }
    for (int kc = 0; kc < 256; ++kc){
      const float4 a0v = *(const float4*)(wr0 + (kc << 3));
      const float4 a1v = *(const float4*)(wr0 + (kc << 3) + 4);
      const float4 b0v = *(const float4*)(wr1 + (kc << 3));
      const float4 b1v = *(const float4*)(wr1 + (kc << 3) + 4);
      const float4 c0v = *(const float4*)(wr2 + (kc << 3));
      const float4 c1v = *(const float4*)(wr2 + (kc << 3) + 4);
      const float4 d0v = *(const float4*)(wr3 + (kc << 3));
      const float4 d1v = *(const float4*)(wr3 + (kc << 3) + 4);
      const float* ap = alds + (kc << 3);
      #pragma unroll
      for (int m = 0; m < 16; ++m){
        const float* a = ap + (m << 11);
        float4 x0 = *(const float4*)(a);
        float4 x1 = *(const float4*)(a + 4);
        acc0[m] = fmaf(a0v.x, x0.x, acc0[m]); acc0[m] = fmaf(a0v.y, x0.y, acc0[m]);
        acc0[m] = fmaf(a0v.z, x0.z, acc0[m]); acc0[m] = fmaf(a0v.w, x0.w, acc0[m]);
        acc0[m] = fmaf(a1v.x, x1.x, acc0[m]); acc0[m] = fmaf(a1v.y, x1.y, acc0[m]);
        acc0[m] = fmaf(a1v.z, x1.z, acc0[m]); acc0[m] = fmaf(a1v.w, x1.w, acc0[m]);
        acc1[m] = fmaf(b0v.x, x0.x, acc1[m]); acc1[m] = fmaf(b0v.y, x0.y, acc1[m]);
        acc1[m] = fmaf(b0v.z, x0.z, acc1[m]); acc1[m] = fmaf(b0v.w, x0.w, acc1[m]);
        acc1[m] = fmaf(b1v.x, x1.x, acc1[m]); acc1[m] = fmaf(b1v.y, x1.y, acc1[m]);
        acc1[m] = fmaf(b1v.z, x1.z, acc1[m]); acc1[m] = fmaf(b1v.w, x1.w, acc1[m]);
        acc2[m] = fmaf(c0v.x, x0.x, acc2[m]); acc2[m] = fmaf(c0v.y, x0.y, acc2[m]);
        acc2[m] = fmaf(c0v.z, x0.z, acc2[m]); acc2[m] = fmaf(c0v.w, x0.w, acc2[m]);
        acc2[m] = fmaf(c1v.x, x1.x, acc2[m]); acc2[m] = fmaf(c1v.y, x1.y, acc2[m]);
        acc2[m] = fmaf(c1v.z, x1.z, acc2[m]); acc2[m] = fmaf(c1v.w, x1.w, acc2[m]);
        acc3[m] = fmaf(d0v.x, x0.x, acc3[m]); acc3[m] = fmaf(d0v.y, x0.y, acc3[m]);
        acc3[m] = fmaf(d0v.z, x0.z, acc3[m]); acc3[m] = fmaf(d0v.w, x0.w, acc3[m]);
        acc3[m] = fmaf(d1v.x, x1.x, acc3[m]); acc3[m] = fmaf(d1v.y, x1.y, acc3[m]);
        acc3[m] = fmaf(d1v.z, x1.z, acc3[m]); acc3[m] = fmaf(d1v.w, x1.w, acc3[m]);
      }
    }
    const float bo0 = bout[n0];
    const float bo1 = bout[n1];
    const float bo2 = bout[n2];
    const float bo3 = bout[n3];
    #pragma unroll
    for (int m = 0; m < 16; ++m){
      io[rbase + ((size_t)m << 11) + n0] = acc0[m] + bo0;
      io[rbase + ((size_t)m << 11) + n1] = acc1[m] + bo1;
      io[rbase + ((size_t)m << 11) + n2] = acc2[m] + bo2;
      io[rbase + ((size_t)m << 11) + n3] = acc3[m] + bo3;
    }
  }
}

extern "C" void kernel_launch(void* const* d_in, const int* in_sizes, int n_in,
                              void* d_out, int out_size, void* d_ws, size_t ws_size,
                              hipStream_t stream)
{
  const float* xin  = (const float*)d_in[0];
  const float* Wih  = (const float*)d_in[1];
  const float* Whh  = (const float*)d_in[2];
  const float* bih  = (const float*)d_in[3];
  const float* bhh  = (const float*)d_in[4];
  const float* Wout = (const float*)d_in[5];
  const float* bout = (const float*)d_in[6];
  float* out = (float*)d_out;

  // workspace: [0,64K) chunk buffer (2 parities x 2048 x 16 B; poison
  // 0xAAAAAAAA never matches tags 1..2047 -> no init pass);
  // [64K, +33.5MB) seq staging; [64K+SEQ, +8.4MB) f16 Wout.
  u32x4* chk16 = (u32x4*)d_ws;
  const size_t SEQ_BYTES = (size_t)2 * 2048 * E * sizeof(float);    // 33.55 MB
  const size_t WF_BYTES  = (size_t)E * E * 2;                       // 8.39 MB
  const bool big  = ws_size >= 65536 + SEQ_BYTES;
  const bool big2 = ws_size >= 65536 + SEQ_BYTES + WF_BYTES;
  float* seqdst = big ? (float*)((char*)d_ws + 65536) : out;
  u32*   wf     = (u32*)((char*)d_ws + 65536 + SEQ_BYTES);

  hipFuncSetAttribute((const void*)lstm_kernel,
                      hipFuncAttributeMaxDynamicSharedMemorySize, SMEM_MAIN);
  hipFuncSetAttribute((const void*)proj_pair16,
                      hipFuncAttributeMaxDynamicSharedMemorySize, SMEM_PROJ);
  hipFuncSetAttribute((const void*)proj_pair_kernel,
                      hipFuncAttributeMaxDynamicSharedMemorySize, SMEM_PROJ);
  hipFuncSetAttribute((const void*)proj_kernel,
                      hipFuncAttributeMaxDynamicSharedMemorySize, SMEM_PROJ);

  if (big2){
    // E*E = 4,194,304 floats / (256 thr x 8 floats) = 2048 blocks exactly
    wout_cvt<<<2048, 256, 0, stream>>>(Wout, wf);
  }

  void* args[] = { (void*)&xin, (void*)&Wih, (void*)&Whh, (void*)&bih, (void*)&bhh,
                   (void*)&chk16, (void*)&seqdst };
  hipLaunchCooperativeKernel((const void*)lstm_kernel, dim3(NBLK), dim3(NTHR),
                             args, SMEM_MAIN, stream);

  if (big2){
    proj_pair16<<<256, 512, SMEM_PROJ, stream>>>(seqdst, out, wf, bout);
  } else if (big){
    proj_pair_kernel<<<256, 512, SMEM_PROJ, stream>>>(seqdst, out, Wout, bout);
  } else {
    proj_kernel<<<256, 256, SMEM_PROJ, stream>>>(out, Wout, bout);
  }
}

// Round 16
// 7683.326 us; speedup vs baseline: 1.0342x; 1.0342x over previous
//
#include <hip/hip_runtime.h>
#include <hip/hip_fp16.h>
#include <stdint.h>

// LSTM, E=2048, B=2, T=2048, ALL I/O float32 (per reference dtypes).
// For t>=1 input==h, so gates = h @ (W_ih+W_hh)^T + (b_ih+b_hh).
// v17 = v15 lstm BYTE-EXACT (proven 7300us) + v16's pipelined proj (373us).
// v16 post-mortem: the [64 rowsel][12] pls re-layout REGRESSED (+273us,
//   bank conflicts 2.5e7 -> 2.06e8, 8x): stride-12 slots alias writer b32
//   stores and reader b128 loads across banks. v15's stride-20 layout was
//   already clean; its 4xb128 tail read was never the binding term.
//   Lesson: LDS layout changes must be bank-audited first. proj prefetch
//   DID help (414 -> 373us) -- kept.
// Step budget (v15 measured): 3.56us = 0.43 FMA-issue + ~0.5 reduce/tail
// + ~2.6 structural exchange (store->LLC->poll RTT x global-max over 256
// producers, 2048 serialized full-chip round-trips; counters: 1.5% HBM,
// 27% VALU -> latency-bound). Weight capacity (131KB/block in VGPRs at
// the 512-thr/128-VGPR cap) forces this topology.
// Kept (verified 7x): f16 packed weights in VGPRs (v_fma_mix), fp32 h in
// padded LDS (stride 36), 16B chunks [pay_b0|tag|pay_b1|tag] (4 dwordx4
// polls/lane), parallel-gate tail, vmcnt(0)+sleep cadence with
// reloads-before-sleep, lgkmcnt-only deposit sync, ONE __syncthreads/step,
// single coalesced 128B publish (v9 law), c in registers, sc0 sc1
// LLC-direct exchange, publish-before-seqout. Protocol: tag-validated
// (poison 0xAAAAAAAA never matches tags 1..2047), relaxed, no fences.
// chk: [parity(2)][2048 chunks] x 16B = 64KB.

#define E 2048
#define NBLK 256
#define NTHR 512
#define HLDS_B 2304            // padded floats per batch: 64 slices * 36
#define PLS_STRIDE 20          // floats per row slot (16 used + 4 pad)
#define PLS_PAR 640            // floats per parity: 32 rows * 20
#define SMEM_MAIN 23680
#define SMEM_PROJ 131072

typedef uint32_t u32;
typedef unsigned long long u64;
typedef unsigned int u32x4 __attribute__((ext_vector_type(4)));
typedef _Float16 hf2 __attribute__((ext_vector_type(2)));

__device__ __forceinline__ float sigf(float x){
  return __builtin_amdgcn_rcpf(1.0f + __expf(-x));
}
__device__ __forceinline__ float tanhfast(float x){
  // 1 - 2/(e^{2x}+1); exp overflow -> rcp(inf)=0 -> 1; underflow -> -1.
  float e = __expf(2.0f * x);
  return 1.0f - 2.0f * __builtin_amdgcn_rcpf(e + 1.0f);
}
__device__ __forceinline__ u32 f16p(float lo, float hi){
  return (u32)__half_as_ushort(__float2half_rn(lo))
       | ((u32)__half_as_ushort(__float2half_rn(hi)) << 16);
}
__device__ __forceinline__ float dot2(u32 a, u32 b, float acc){
  return __builtin_amdgcn_fdot2(__builtin_bit_cast(hf2, a),
                                __builtin_bit_cast(hf2, b), acc, false);
}

// one row x 8 k, both batches: 16 FMAs from 4 packed-f16 weight pairs
#define ROWFMA8(W0, W1, W2, W3, A0, A1) \
  A0 = fmaf(__low2float(W0),  p0.x, A0); A0 = fmaf(__high2float(W0), p0.y, A0); \
  A0 = fmaf(__low2float(W1),  p0.z, A0); A0 = fmaf(__high2float(W1), p0.w, A0); \
  A0 = fmaf(__low2float(W2),  p1.x, A0); A0 = fmaf(__high2float(W2), p1.y, A0); \
  A0 = fmaf(__low2float(W3),  p1.z, A0); A0 = fmaf(__high2float(W3), p1.w, A0); \
  A1 = fmaf(__low2float(W0),  q0.x, A1); A1 = fmaf(__high2float(W0), q0.y, A1); \
  A1 = fmaf(__low2float(W1),  q0.z, A1); A1 = fmaf(__high2float(W1), q0.w, A1); \
  A1 = fmaf(__low2float(W2),  q1.x, A1); A1 = fmaf(__high2float(W2), q1.y, A1); \
  A1 = fmaf(__low2float(W3),  q1.z, A1); A1 = fmaf(__high2float(W3), q1.w, A1);

// tag-check both 8B halves of chunk slot J (QJ = [pay0,tag0,pay1,tag1])
#define CHKQ(J, QJ) \
  if (pend & (1 << (2*(J)))){ \
    if ((QJ).y == tag){ \
      hlds[cd0[J]] = __uint_as_float((QJ).x); pend &= ~(1 << (2*(J))); } } \
  if (pend & (2 << (2*(J)))){ \
    if ((QJ).w == tag){ \
      hlds[cd1[J]] = __uint_as_float((QJ).z); pend &= ~(2 << (2*(J))); } }

// 4 LLC-direct dwordx4 samples (1 KB contiguous per wave per load)
#define ISSUE4Q(Q0, Q1, Q2, Q3) \
  asm volatile( \
    "global_load_dwordx4 %0, %4, off sc0 sc1\n\t" \
    "global_load_dwordx4 %1, %4, off offset:1024 sc0 sc1\n\t" \
    "global_load_dwordx4 %2, %4, off offset:2048 sc0 sc1\n\t" \
    "global_load_dwordx4 %3, %4, off offset:3072 sc0 sc1" \
    : "=&v"(Q0), "=&v"(Q1), "=&v"(Q2), "=&v"(Q3) \
    : "v"(src) : "memory")

// exec-masked reload of chunk J if either half pending
#define RELOADQ(J, QJ, OFS) \
  if (pend & (3 << (2*(J)))){ \
    asm volatile("global_load_dwordx4 %0, %1, off offset:" OFS " sc0 sc1" \
                 : "=v"(QJ) : "v"(src) : "memory"); \
  }

__global__ void __launch_bounds__(NTHR, 1) lstm_kernel(
    const float* __restrict__ xin, const float* __restrict__ Wih,
    const float* __restrict__ Whh, const float* __restrict__ bih,
    const float* __restrict__ bhh, u32x4* __restrict__ chk16,
    float* __restrict__ seqout)
{
  extern __shared__ char smem[];
  float* hlds = (float*)smem;                    // [2][2304] = 18432 B (padded h)
  float* pls  = (float*)(smem + 18432);          // [2][640]  =  5120 B partials
  float* bias = (float*)(smem + 23552);          // [32]

  const int tid  = threadIdx.x;
  const int blk  = blockIdx.x;
  const int e0   = blk << 3;                     // this block owns h elems e0..e0+7
  const int lane = tid & 63;
  const int wv   = tid >> 6;                     // wave 0..7, k-slice [wv*256, +256)
  const int rg   = lane >> 3;                    // row group: rows rg*4..rg*4+3
  const int ksl  = lane & 7;                     // 32-k sub-slice within wave
  const int ks   = (wv << 3) + ksl;              // global 32-k slice 0..63
  const int k0   = ks << 5;

  if (tid < 32){
    const int grow = ((tid >> 3) << 11) + e0 + (tid & 7);
    bias[tid] = bih[grow] + bhh[grow];
  }
  // x for t=0, written in the padded h layout
  for (int i = tid; i < 2 * E; i += NTHR){
    const int b = i >> 11, k = i & 2047;
    hlds[b * HLDS_B + (k >> 5) * 36 + (k & 31)] = xin[i];
  }
  __syncthreads();

  const float* hb0 = hlds + ks * 36;             // batch 0, own 32-k slice
  const float* hb1 = hlds + HLDS_B + ks * 36;    // batch 1

  // ---- fused: build f16 Wc = Wih + Whh into registers (64 half2) AND
  //      compute t=0 gates = x @ W_ih^T in full fp32 (h=0 at t=0) ----
  __half2 wh[64];
  float acc0[4] = {0.f, 0.f, 0.f, 0.f};
  float acc1[4] = {0.f, 0.f, 0.f, 0.f};
  #pragma unroll
  for (int rr = 0; rr < 4; ++rr){
    const int row  = (rg << 2) + rr;             // 0..31 = gate*8 + eoff
    const int grow = ((row >> 3) << 11) + e0 + (row & 7);
    const float* pa = Wih + (size_t)grow * E + k0;
    const float* pb = Whh + (size_t)grow * E + k0;
    #pragma unroll
    for (int c = 0; c < 8; ++c){                 // 4 k per chunk
      float4 a = *(const float4*)(pa + (c << 2));
      float4 b = *(const float4*)(pb + (c << 2));
      wh[(rr << 4) + (c << 1)    ] =
        __halves2half2(__float2half_rn(a.x + b.x), __float2half_rn(a.y + b.y));
      wh[(rr << 4) + (c << 1) + 1] =
        __halves2half2(__float2half_rn(a.z + b.z), __float2half_rn(a.w + b.w));
      float4 x0 = *(const float4*)(hb0 + (c << 2));
      float4 x1 = *(const float4*)(hb1 + (c << 2));
      acc0[rr] = fmaf(a.x, x0.x, acc0[rr]); acc0[rr] = fmaf(a.y, x0.y, acc0[rr]);
      acc0[rr] = fmaf(a.z, x0.z, acc0[rr]); acc0[rr] = fmaf(a.w, x0.w, acc0[rr]);
      acc1[rr] = fmaf(a.x, x1.x, acc1[rr]); acc1[rr] = fmaf(a.y, x1.y, acc1[rr]);
      acc1[rr] = fmaf(a.z, x1.z, acc1[rr]); acc1[rr] = fmaf(a.w, x1.w, acc1[rr]);
    }
  }

  const float br = bias[lane & 31];              // hoisted (used by wave 0)
  float creg = 0.0f;                             // cell state (cell lanes)

  // poll mapping: chunk c == element e; wave wv polls its own k-slice
  // [wv*256, +256): 4 chunks/lane, each load = 1 KB contiguous per wave.
  int cd0[4], cd1[4];
  #pragma unroll
  for (int j = 0; j < 4; ++j){
    const int e = (wv << 8) + (j << 6) + lane;
    cd0[j] = (e >> 5) * 36 + (e & 31);           // batch 0 deposit
    cd1[j] = HLDS_B + cd0[j];                    // batch 1 deposit
  }

  for (int t = 0; t < 2048; ++t){
    // wave-level pre-reduce across the 8 k-sub-slices (ksl = lane bits 0..2)
    #pragma unroll
    for (int m = 1; m <= 4; m <<= 1){
      #pragma unroll
      for (int rr = 0; rr < 4; ++rr){
        acc0[rr] += __shfl_xor(acc0[rr], m, 64);
        acc1[rr] += __shfl_xor(acc1[rr], m, 64);
      }
    }
    if (ksl == 0){                               // 8 lanes/wave publish partials
      float2* pw = (float2*)(pls + (t & 1) * PLS_PAR);
      #pragma unroll
      for (int rr = 0; rr < 4; ++rr)
        pw[((rg << 2) + rr) * (PLS_STRIDE / 2) + wv] = make_float2(acc0[rr], acc1[rr]);
    }
    __syncthreads();                             // the ONLY barrier per step

    if (wv == 0){                                // parallel-gate tail
      const int r = lane & 31;                   // row = gate*8 + eoff
      const int b = lane >> 5;
      const float* rp = pls + (t & 1) * PLS_PAR + r * PLS_STRIDE;
      float4 v0 = *(const float4*)(rp);
      float4 v1 = *(const float4*)(rp + 4);
      float4 v2 = *(const float4*)(rp + 8);
      float4 v3 = *(const float4*)(rp + 12);
      float s = br + (b ? (v0.y + v0.w + v1.y + v1.w + v2.y + v2.w + v3.y + v3.w)
                        : (v0.x + v0.z + v1.x + v1.z + v2.x + v2.z + v3.x + v3.z));
      // own gate's nonlinearity in parallel: tanh(s) = 2*sig(2s)-1 (g==2)
      const int g = r >> 3;                      // 0=i, 1=f, 2=g, 3=o
      const float arg = (g == 2) ? (s + s) : s;
      const float t0v = sigf(arg);
      const float nl  = (g == 2) ? (2.0f * t0v - 1.0f) : t0v;
      const float SF = __shfl(nl, (lane + 8)  & 63, 64);   // sig(f) to cell lanes
      const float TG = __shfl(nl, (lane + 16) & 63, 64);   // tanh(g)
      const float SO = __shfl(nl, (lane + 24) & 63, 64);   // sig(o)
      if (r < 8){                                // cell lanes (g==0: nl=sig(i))
        const float cn = SF * creg + nl * TG;
        const float hn = SO * tanhfast(cn);
        creg = cn;
        const u32 h32 = __float_as_uint(hn);
        const u32 oth = (u32)__shfl((int)h32, (lane + 32) & 63, 64);  // b1 value
        if (t < 2047 && b == 0){                 // publish: ONE 128B store
          const u32 tg = (u32)(t + 1);
          u32x4 pk; pk.x = h32; pk.y = tg; pk.z = oth; pk.w = tg;
          u32x4* dst = chk16 + (((t + 1) & 1) << 11) + e0 + lane;
          asm volatile("global_store_dwordx4 %0, %1, off sc0 sc1"
                       :: "v"(dst), "v"(pk) : "memory");
        }
        seqout[(((size_t)b << 11) + (size_t)t) * E + e0 + r] = hn;
      }
    }
    if (t == 2047) break;

    {   // poll: LLC-direct 4x dwordx4; reloads issued BEFORE sleep
      const u32x4* src = (const u32x4*)chk16 + (((t + 1) & 1) << 11)
                       + (wv << 8) + lane;
      const u32 tag = (u32)(t + 1);
      u32x4 q0, q1, q2, q3;
      ISSUE4Q(q0, q1, q2, q3);
      asm volatile("s_waitcnt vmcnt(0)" ::: "memory");
      int pend = 0xFF;
      while (true){
        CHKQ(0, q0) CHKQ(1, q1) CHKQ(2, q2) CHKQ(3, q3)
        if (pend == 0) break;
        RELOADQ(0, q0, "0")    RELOADQ(1, q1, "1024")
        RELOADQ(2, q2, "2048") RELOADQ(3, q3, "3072")
        __builtin_amdgcn_s_sleep(1);
        asm volatile("s_waitcnt vmcnt(0)" ::: "memory");
      }
      // own ds_writes visible to all lanes of this wave (wave-synchronous)
      asm volatile("s_waitcnt lgkmcnt(0)" ::: "memory");
      __builtin_amdgcn_sched_barrier(0);
    }

    // compute acc(t+1): h @ Wc^T, weights in f16 registers
    #pragma unroll
    for (int rr = 0; rr < 4; ++rr){ acc0[rr] = 0.f; acc1[rr] = 0.f; }
    #pragma unroll
    for (int c8 = 0; c8 < 4; ++c8){              // 8 k per chunk
      float4 p0 = *(const float4*)(hb0 + (c8 << 3));
      float4 p1 = *(const float4*)(hb0 + (c8 << 3) + 4);
      float4 q0 = *(const float4*)(hb1 + (c8 << 3));
      float4 q1 = *(const float4*)(hb1 + (c8 << 3) + 4);
      #pragma unroll
      for (int rr = 0; rr < 4; ++rr){
        ROWFMA8(wh[(rr << 4) + (c8 << 2)],     wh[(rr << 4) + (c8 << 2) + 1],
                wh[(rr << 4) + (c8 << 2) + 2], wh[(rr << 4) + (c8 << 2) + 3],
                acc0[rr], acc1[rr]);
      }
    }
  }
}

// Wout f32 -> packed f16 (one-shot pre-pass into workspace).
// Grid: E*E / (256*8) = 2048 blocks EXACTLY (v14's 4096 was OOB).
__global__ void wout_cvt(const float* __restrict__ w, u32* __restrict__ o)
{
  const size_t i = (((size_t)blockIdx.x << 8) + threadIdx.x) << 3;  // 8 floats
  float4 a = *(const float4*)(w + i);
  float4 b = *(const float4*)(w + i + 4);
  uint4 r;
  r.x = f16p(a.x, a.y); r.y = f16p(a.z, a.w);
  r.z = f16p(b.x, b.y); r.w = f16p(b.z, b.w);
  *(uint4*)(o + (i >> 1)) = r;
}

// proj PAIR path, f16 Wout + v_dot2 + software-pipelined weight stream:
// blocks 2b,2b+1 share rows 32b..+31 (f16-staged from WS seq, 128 KB LDS);
// block computes one 1024-col half, 2 cols/thread, 512 thr (2 waves/SIMD).
__global__ void __launch_bounds__(512, 1) proj_pair16(
    const float* __restrict__ src, float* __restrict__ io,
    const u32* __restrict__ wf, const float* __restrict__ bout)
{
  extern __shared__ char smem[];
  u32* ah = (u32*)smem;                        // [32 rows][1024] half2 = 128 KB
  const int tid = threadIdx.x;
  const int blk = blockIdx.x;
  const size_t rbase = (size_t)(blk >> 1) * 32 * E;
  const int ch = (blk & 1) << 10;              // column-half base

  for (int idx = tid; idx < 32768; idx += 512){   // 32*2048 halves / 2
    const float2 v = *(const float2*)(src + rbase + ((size_t)idx << 1));
    ah[idx] = f16p(v.x, v.y);
  }
  __syncthreads();

  const int n0 = ch + tid;                     // 2 cols: n0, n0+512
  const int n1 = n0 + 512;
  const u32* wr0 = wf + (size_t)n0 * 1024;     // 1024 u32 (2048 halves) per row
  const u32* wr1 = wf + (size_t)n1 * 1024;
  float acc0[32], acc1[32];
  #pragma unroll
  for (int m = 0; m < 32; ++m){ acc0[m] = 0.0f; acc1[m] = 0.0f; }

  uint4 wa = *(const uint4*)(wr0);             // prefetched weight pair
  uint4 wb = *(const uint4*)(wr1);
  for (int kc = 0; kc < 256; ++kc){            // 8 k per iter
    uint4 wa_n, wb_n;
    if (kc < 255){                             // prefetch next while computing
      wa_n = *(const uint4*)(wr0 + ((kc + 1) << 2));
      wb_n = *(const uint4*)(wr1 + ((kc + 1) << 2));
    }
    const u32* hp = ah + (kc << 2);
    #pragma unroll
    for (int m = 0; m < 32; ++m){
      const uint4 hv = *(const uint4*)(hp + (m << 10));  // 8 halves, broadcast
      acc0[m] = dot2(wa.x, hv.x, acc0[m]);
      acc0[m] = dot2(wa.y, hv.y, acc0[m]);
      acc0[m] = dot2(wa.z, hv.z, acc0[m]);
      acc0[m] = dot2(wa.w, hv.w, acc0[m]);
      acc1[m] = dot2(wb.x, hv.x, acc1[m]);
      acc1[m] = dot2(wb.y, hv.y, acc1[m]);
      acc1[m] = dot2(wb.z, hv.z, acc1[m]);
      acc1[m] = dot2(wb.w, hv.w, acc1[m]);
    }
    wa = wa_n; wb = wb_n;
  }
  const float bo0 = bout[n0];
  const float bo1 = bout[n1];
  #pragma unroll
  for (int m = 0; m < 32; ++m){
    io[rbase + ((size_t)m << 11) + n0] = acc0[m] + bo0;
    io[rbase + ((size_t)m << 11) + n1] = acc1[m] + bo1;
  }
}

// Fallback 1 (v13-proven): pair path, f32 Wout.
__global__ void __launch_bounds__(512, 1) proj_pair_kernel(
    const float* __restrict__ src, float* __restrict__ io,
    const float* __restrict__ Wout, const float* __restrict__ bout)
{
  extern __shared__ char smem[];
  u32* ah = (u32*)smem;
  const int tid = threadIdx.x;
  const int blk = blockIdx.x;
  const size_t rbase = (size_t)(blk >> 1) * 32 * E;
  const int ch = (blk & 1) << 10;

  for (int idx = tid; idx < 32768; idx += 512){
    const float2 v = *(const float2*)(src + rbase + ((size_t)idx << 1));
    ah[idx] = f16p(v.x, v.y);
  }
  __syncthreads();

  const int n0 = ch + tid;
  const int n1 = n0 + 512;
  const float* wr0 = Wout + (size_t)n0 * E;
  const float* wr1 = Wout + (size_t)n1 * E;
  float acc0[32], acc1[32];
  #pragma unroll
  for (int m = 0; m < 32; ++m){ acc0[m] = 0.0f; acc1[m] = 0.0f; }
  for (int kc = 0; kc < 256; ++kc){
    const float4 a0v = *(const float4*)(wr0 + (kc << 3));
    const float4 a1v = *(const float4*)(wr0 + (kc << 3) + 4);
    const float4 b0v = *(const float4*)(wr1 + (kc << 3));
    const float4 b1v = *(const float4*)(wr1 + (kc << 3) + 4);
    const u32* hp = ah + (kc << 2);
    #pragma unroll
    for (int m = 0; m < 32; ++m){
      const uint4 hv = *(const uint4*)(hp + (m << 10));
      const __half2 h0 = __builtin_bit_cast(__half2, hv.x);
      const __half2 h1 = __builtin_bit_cast(__half2, hv.y);
      const __half2 h2 = __builtin_bit_cast(__half2, hv.z);
      const __half2 h3 = __builtin_bit_cast(__half2, hv.w);
      const float x0 = __low2float(h0), x1 = __high2float(h0);
      const float x2 = __low2float(h1), x3 = __high2float(h1);
      const float x4 = __low2float(h2), x5 = __high2float(h2);
      const float x6 = __low2float(h3), x7 = __high2float(h3);
      acc0[m] = fmaf(a0v.x, x0, acc0[m]); acc0[m] = fmaf(a0v.y, x1, acc0[m]);
      acc0[m] = fmaf(a0v.z, x2, acc0[m]); acc0[m] = fmaf(a0v.w, x3, acc0[m]);
      acc0[m] = fmaf(a1v.x, x4, acc0[m]); acc0[m] = fmaf(a1v.y, x5, acc0[m]);
      acc0[m] = fmaf(a1v.z, x6, acc0[m]); acc0[m] = fmaf(a1v.w, x7, acc0[m]);
      acc1[m] = fmaf(b0v.x, x0, acc1[m]); acc1[m] = fmaf(b0v.y, x1, acc1[m]);
      acc1[m] = fmaf(b0v.z, x2, acc1[m]); acc1[m] = fmaf(b0v.w, x3, acc1[m]);
      acc1[m] = fmaf(b1v.x, x4, acc1[m]); acc1[m] = fmaf(b1v.y, x5, acc1[m]);
      acc1[m] = fmaf(b1v.z, x6, acc1[m]); acc1[m] = fmaf(b1v.w, x7, acc1[m]);
    }
  }
  const float bo0 = bout[n0];
  const float bo1 = bout[n1];
  #pragma unroll
  for (int m = 0; m < 32; ++m){
    io[rbase + ((size_t)m << 11) + n0] = acc0[m] + bo0;
    io[rbase + ((size_t)m << 11) + n1] = acc1[m] + bo1;
  }
}

// Fallback 2 (v10-proven, tiny ws): in-place, 16 rows f32-staged.
__global__ void __launch_bounds__(256, 1) proj_kernel(
    float* __restrict__ io, const float* __restrict__ Wout,
    const float* __restrict__ bout)
{
  extern __shared__ char smem[];
  float* alds = (float*)smem;
  const int tid = threadIdx.x;
  const size_t rbase = (size_t)blockIdx.x * 16 * E;

  for (int idx = tid; idx < 8192; idx += 256){
    float4 v = *(const float4*)(io + rbase + ((size_t)idx << 2));
    *(float4*)(alds + (idx << 2)) = v;
  }
  __syncthreads();

  for (int p = 0; p < 2; ++p){
    const int n0 = (p << 10) + tid;
    const int n1 = n0 + 256;
    const int n2 = n0 + 512;
    const int n3 = n0 + 768;
    const float* wr0 = Wout + (size_t)n0 * E;
    const float* wr1 = Wout + (size_t)n1 * E;
    const float* wr2 = Wout + (size_t)n2 * E;
    const float* wr3 = Wout + (size_t)n3 * E;
    float acc0[16], acc1[16], acc2[16], acc3[16];
    #pragma unroll
    for (int m = 0; m < 16; ++m){
      acc0[m] = 0.0f; acc1[m] = 0.0f; acc2[m] = 0.0f; acc3[m] = 0.0f;
    }
    for (int kc = 0; kc < 256; ++kc){
      const float4 a0v = *(const float4*)(wr0 + (kc << 3));
      const float4 a1v = *(const float4*)(wr0 + (kc << 3) + 4);
      const float4 b0v = *(const float4*)(wr1 + (kc << 3));
      const float4 b1v = *(const float4*)(wr1 + (kc << 3) + 4);
      const float4 c0v = *(const float4*)(wr2 + (kc << 3));
      const float4 c1v = *(const float4*)(wr2 + (kc << 3) + 4);
      const float4 d0v = *(const float4*)(wr3 + (kc << 3));
      const float4 d1v = *(const float4*)(wr3 + (kc << 3) + 4);
      const float* ap = alds + (kc << 3);
      #pragma unroll
      for (int m = 0; m < 16; ++m){
        const float* a = ap + (m << 11);
        float4 x0 = *(const float4*)(a);
        float4 x1 = *(const float4*)(a + 4);
        acc0[m] = fmaf(a0v.x, x0.x, acc0[m]); acc0[m] = fmaf(a0v.y, x0.y, acc0[m]);
        acc0[m] = fmaf(a0v.z, x0.z, acc0[m]); acc0[m] = fmaf(a0v.w, x0.w, acc0[m]);
        acc0[m] = fmaf(a1v.x, x1.x, acc0[m]); acc0[m] = fmaf(a1v.y, x1.y, acc0[m]);
        acc0[m] = fmaf(a1v.z, x1.z, acc0[m]); acc0[m] = fmaf(a1v.w, x1.w, acc0[m]);
        acc1[m] = fmaf(b0v.x, x0.x, acc1[m]); acc1[m] = fmaf(b0v.y, x0.y, acc1[m]);
        acc1[m] = fmaf(b0v.z, x0.z, acc1[m]); acc1[m] = fmaf(b0v.w, x0.w, acc1[m]);
        acc1[m] = fmaf(b1v.x, x1.x, acc1[m]); acc1[m] = fmaf(b1v.y, x1.y, acc1[m]);
        acc1[m] = fmaf(b1v.z, x1.z, acc1[m]); acc1[m] = fmaf(b1v.w, x1.w, acc1[m]);
        acc2[m] = fmaf(c0v.x, x0.x, acc2[m]); acc2[m] = fmaf(c0v.y, x0.y, acc2[m]);
        acc2[m] = fmaf(c0v.z, x0.z, acc2[m]); acc2[m] = fmaf(c0v.w, x0.w, acc2[m]);
        acc2[m] = fmaf(c1v.x, x1.x, acc2[m]); acc2[m] = fmaf(c1v.y, x1.y, acc2[m]);
        acc2[m] = fmaf(c1v.z, x1.z, acc2[m]); acc2[m] = fmaf(c1v.w, x1.w, acc2[m]);
        acc3[m] = fmaf(d0v.x, x0.x, acc3[m]); acc3[m] = fmaf(d0v.y, x0.y, acc3[m]);
        acc3[m] = fmaf(d0v.z, x0.z, acc3[m]); acc3[m] = fmaf(d0v.w, x0.w, acc3[m]);
        acc3[m] = fmaf(d1v.x, x1.x, acc3[m]); acc3[m] = fmaf(d1v.y, x1.y, acc3[m]);
        acc3[m] = fmaf(d1v.z, x1.z, acc3[m]); acc3[m] = fmaf(d1v.w, x1.w, acc3[m]);
      }
    }
    const float bo0 = bout[n0];
    const float bo1 = bout[n1];
    const float bo2 = bout[n2];
    const float bo3 = bout[n3];
    #pragma unroll
    for (int m = 0; m < 16; ++m){
      io[rbase + ((size_t)m << 11) + n0] = acc0[m] + bo0;
      io[rbase + ((size_t)m << 11) + n1] = acc1[m] + bo1;
      io[rbase + ((size_t)m << 11) + n2] = acc2[m] + bo2;
      io[rbase + ((size_t)m << 11) + n3] = acc3[m] + bo3;
    }
  }
}

extern "C" void kernel_launch(void* const* d_in, const int* in_sizes, int n_in,
                              void* d_out, int out_size, void* d_ws, size_t ws_size,
                              hipStream_t stream)
{
  const float* xin  = (const float*)d_in[0];
  const float* Wih  = (const float*)d_in[1];
  const float* Whh  = (const float*)d_in[2];
  const float* bih  = (const float*)d_in[3];
  const float* bhh  = (const float*)d_in[4];
  const float* Wout = (const float*)d_in[5];
  const float* bout = (const float*)d_in[6];
  float* out = (float*)d_out;

  // workspace: [0,64K) chunk buffer (2 parities x 2048 x 16 B; poison
  // 0xAAAAAAAA never matches tags 1..2047 -> no init pass);
  // [64K, +33.5MB) seq staging; [64K+SEQ, +8.4MB) f16 Wout.
  u32x4* chk16 = (u32x4*)d_ws;
  const size_t SEQ_BYTES = (size_t)2 * 2048 * E * sizeof(float);    // 33.55 MB
  const size_t WF_BYTES  = (size_t)E * E * 2;                       // 8.39 MB
  const bool big  = ws_size >= 65536 + SEQ_BYTES;
  const bool big2 = ws_size >= 65536 + SEQ_BYTES + WF_BYTES;
  float* seqdst = big ? (float*)((char*)d_ws + 65536) : out;
  u32*   wf     = (u32*)((char*)d_ws + 65536 + SEQ_BYTES);

  hipFuncSetAttribute((const void*)lstm_kernel,
                      hipFuncAttributeMaxDynamicSharedMemorySize, SMEM_MAIN);
  hipFuncSetAttribute((const void*)proj_pair16,
                      hipFuncAttributeMaxDynamicSharedMemorySize, SMEM_PROJ);
  hipFuncSetAttribute((const void*)proj_pair_kernel,
                      hipFuncAttributeMaxDynamicSharedMemorySize, SMEM_PROJ);
  hipFuncSetAttribute((const void*)proj_kernel,
                      hipFuncAttributeMaxDynamicSharedMemorySize, SMEM_PROJ);

  if (big2){
    // E*E = 4,194,304 floats / (256 thr x 8 floats) = 2048 blocks exactly
    wout_cvt<<<2048, 256, 0, stream>>>(Wout, wf);
  }

  void* args[] = { (void*)&xin, (void*)&Wih, (void*)&Whh, (void*)&bih, (void*)&bhh,
                   (void*)&chk16, (void*)&seqdst };
  hipLaunchCooperativeKernel((const void*)lstm_kernel, dim3(NBLK), dim3(NTHR),
                             args, SMEM_MAIN, stream);

  if (big2){
    proj_pair16<<<256, 512, SMEM_PROJ, stream>>>(seqdst, out, wf, bout);
  } else if (big){
    proj_pair_kernel<<<256, 512, SMEM_PROJ, stream>>>(seqdst, out, Wout, bout);
  } else {
    proj_kernel<<<256, 256, SMEM_PROJ, stream>>>(out, Wout, bout);
  }
}